// Round 13
// baseline (230.520 us; speedup 1.0000x reference)
//
#include <hip/hip_runtime.h>
#include <hip/hip_bf16.h>
#include <hip/hip_fp16.h>

// Edge-MLP: score[e] = W3·relu(W2·relu(W1u·h[src[e]] + W1v·h[dst[e]] + b1) + b2) + b3
// R13 (= audited R12, resubmitted after two infra failures): counting-sort edges by
// src>>9 + XCD-chunked contiguous tile assignment -> per-XCD src working set ~3.2MB
// fits 4MB L2 -> src gathers L2-hit. Compute core = HW-verified v4 (32x32x16, W in
// regs, lane-local L3). out via perm. Post-loop vmcnt(0) drain. Fallbacks: v4, v1.

#define N_NODES 100000
#define N_EDGES 500000
#define F       128
#define HID     128
#define TE      32
#define NT      (N_EDGES / TE)               // 15625, exact
#define GRID    1024
#define BLOCK   256                          // 4 waves = 4 mh blocks
#define TPB     16                           // tiles per block (1024*16 >= 15625)

#define NB      196                          // src buckets (src>>9)
#define HB      256                          // histogram blocks
#define HCHUNK  1954                         // edges per hist block (256*1954 >= 500000)

typedef _Float16 f16x8  __attribute__((ext_vector_type(8)));
typedef float    f32x16 __attribute__((ext_vector_type(16)));

typedef __attribute__((address_space(3))) unsigned int  lds_u32;
typedef __attribute__((address_space(1))) const unsigned int glb_u32;

__device__ __forceinline__ void load_lds16(const void* g, void* l) {
    __builtin_amdgcn_global_load_lds((glb_u32*)g, (lds_u32*)l, 16, 0, 0);
}
__device__ __forceinline__ void bar_lgkm() {
    asm volatile("s_waitcnt lgkmcnt(0)" ::: "memory");
    __builtin_amdgcn_s_barrier();
    __builtin_amdgcn_sched_barrier(0);
}
__device__ __forceinline__ void bar_vm() {
    asm volatile("s_waitcnt vmcnt(0) lgkmcnt(0)" ::: "memory");
    __builtin_amdgcn_s_barrier();
    __builtin_amdgcn_sched_barrier(0);
}

// ---------------- h -> f16 conversion ----------------
__global__ __launch_bounds__(256) void h_to_f16(const float* __restrict__ h,
                                                _Float16* __restrict__ h16) {
    const int i = (blockIdx.x * 256 + threadIdx.x) * 8;   // 12.8M elems exact
    float4 a = *(const float4*)(h + i);
    float4 b = *(const float4*)(h + i + 4);
    f16x8 v;
    v[0] = (_Float16)a.x; v[1] = (_Float16)a.y; v[2] = (_Float16)a.z; v[3] = (_Float16)a.w;
    v[4] = (_Float16)b.x; v[5] = (_Float16)b.y; v[6] = (_Float16)b.z; v[7] = (_Float16)b.w;
    *(f16x8*)(h16 + i) = v;
}

// ---------------- counting sort by src>>9: hist / scan / scatter ----------------
__global__ __launch_bounds__(256) void hist_kernel(const int* __restrict__ src,
                                                   unsigned* __restrict__ bh) {
    __shared__ unsigned hs[NB];
    const int blk = blockIdx.x, tid = threadIdx.x;
    if (tid < NB) hs[tid] = 0;
    __syncthreads();
    const int base = blk * HCHUNK;
    for (int i = tid; i < HCHUNK; i += 256) {
        const int e = base + i;
        if (e < N_EDGES) atomicAdd(&hs[src[e] >> 9], 1u);
    }
    __syncthreads();
    if (tid < NB) bh[blk * NB + tid] = hs[tid];
}

__global__ __launch_bounds__(256) void scan_kernel(unsigned* __restrict__ bh) {
    __shared__ unsigned tot[NB];
    const int j = threadIdx.x;
    if (j < NB) {
        unsigned off = 0;
        for (int b = 0; b < HB; b += 8) {               // 8-wide to keep loads in flight
            unsigned t[8];
            #pragma unroll
            for (int k = 0; k < 8; ++k) t[k] = bh[(b + k) * NB + j];
            #pragma unroll
            for (int k = 0; k < 8; ++k) { bh[(b + k) * NB + j] = off; off += t[k]; }
        }
        tot[j] = off;
    }
    __syncthreads();
    if (j == 0) {                                        // serial 196-elem exclusive scan
        unsigned run = 0;
        for (int k = 0; k < NB; ++k) { unsigned t = tot[k]; tot[k] = run; run += t; }
    }
    __syncthreads();
    if (j < NB) {
        const unsigned base = tot[j];
        for (int b = 0; b < HB; b += 8) {
            unsigned t[8];
            #pragma unroll
            for (int k = 0; k < 8; ++k) t[k] = bh[(b + k) * NB + j];
            #pragma unroll
            for (int k = 0; k < 8; ++k) bh[(b + k) * NB + j] = t[k] + base;
        }
    }
}

__global__ __launch_bounds__(256) void scatter_kernel(const int* __restrict__ src,
                                                      const int* __restrict__ dst,
                                                      const unsigned* __restrict__ bh,
                                                      int* __restrict__ s_srt,
                                                      int* __restrict__ d_srt,
                                                      int* __restrict__ perm) {
    __shared__ unsigned cnt[NB];
    const int blk = blockIdx.x, tid = threadIdx.x;
    if (tid < NB) cnt[tid] = bh[blk * NB + tid];
    __syncthreads();
    const int base = blk * HCHUNK;
    for (int i = tid; i < HCHUNK; i += 256) {
        const int e = base + i;
        if (e < N_EDGES) {
            const int s = src[e];
            const unsigned pos = atomicAdd(&cnt[s >> 9], 1u);
            s_srt[pos] = s;
            d_srt[pos] = dst[e];
            perm[pos]  = e;
        }
    }
}

// ---------------- fused edge kernel, v6 (= v4 core + sorted edges) ----------------
__global__ __launch_bounds__(BLOCK) void edge_mlp_v6(
    const _Float16* __restrict__ h16,
    const int*   __restrict__ s_srt,
    const int*   __restrict__ d_srt,
    const int*   __restrict__ perm,
    const float* __restrict__ W1,   // [128][256]
    const float* __restrict__ b1,
    const float* __restrict__ W2,   // [128][128]
    const float* __restrict__ b2,
    const float* __restrict__ W3,   // [1][128]
    const float* __restrict__ b3,
    float*       __restrict__ out)
{
    // contiguous sorted-tile chunk per block, chunks grouped per XCD
    const int vb   = (blockIdx.x & 7) * 128 + (blockIdx.x >> 3);
    const int tbeg = vb * TPB;
    if (tbeg >= NT) return;
    const int tend = (tbeg + TPB < NT) ? tbeg + TPB : NT;

    __shared__ __align__(128) char Alds[2 * TE * 512];   // 2 x 16KB, swz ^((e&15)<<4)
    __shared__ __align__(128) char Xlds[TE * 256];       // 8KB
    float* Spart = (float*)Xlds;                         // [4][32] alias (barrier-protected)

    const int tid  = threadIdx.x;
    const int wave = tid >> 6;
    const int lane = tid & 63;
    const int mh   = wave;
    const int col  = lane & 31;
    const int h    = lane >> 5;

    // ---- weight slices into registers (A-operand 32x32x16: row=lane&31, k=8h+j) ----
    f16x8 w1a[16];
    #pragma unroll
    for (int kt = 0; kt < 16; ++kt) {
        const float* p = W1 + (mh * 32 + col) * 256 + kt * 16 + 8 * h;
        f16x8 v;
        #pragma unroll
        for (int j = 0; j < 8; ++j) v[j] = (_Float16)p[j];
        w1a[kt] = v;
    }
    f16x8 w2a[8];
    #pragma unroll
    for (int kt = 0; kt < 8; ++kt) {
        const float* p = W2 + (mh * 32 + col) * 128 + kt * 16 + 8 * h;
        f16x8 v;
        #pragma unroll
        for (int j = 0; j < 8; ++j) v[j] = (_Float16)p[j];
        w2a[kt] = v;
    }
    float b1pl[16], b2pl[16], w3pl[16];
    #pragma unroll
    for (int r = 0; r < 16; ++r) {
        const int row = mh * 32 + (r & 3) + 8 * (r >> 2) + 4 * h;
        b1pl[r] = b1[row];
        b2pl[r] = b2[row];
        w3pl[r] = W3[row];
    }
    const float b3v = b3[0];

    // ---- gather geometry (verified v4): DMA instr i=wave*4+j, lane l -> byte i*1024+l*16
    //   e = 2i + (l>>5); logical chunk = (l&31)^(e&15); which = bit4; k16 = (l&15)^(e&15)
    int eloc[4], k16v[4];
    #pragma unroll
    for (int j = 0; j < 4; ++j) {
        const int i = wave * 4 + j;
        eloc[j] = 2 * i + h;
        k16v[j] = (lane & 15) ^ (eloc[j] & 15);
    }
    const int whichv = (lane >> 4) & 1;
    const int* idxp  = whichv ? d_srt : s_srt;

    int nodeCur[4], nodeNext[4];
    #pragma unroll
    for (int j = 0; j < 4; ++j) nodeCur[j] = idxp[tbeg * TE + eloc[j]];
    #pragma unroll
    for (int j = 0; j < 4; ++j) {
        const _Float16* g = h16 + (size_t)nodeCur[j] * F + k16v[j] * 8;
        load_lds16(g, Alds + (wave * 4 + j) * 1024);
    }
    {
        int tn = tbeg + 1; if (tn > NT - 1) tn = NT - 1;
        #pragma unroll
        for (int j = 0; j < 4; ++j) nodeNext[j] = idxp[tn * TE + eloc[j]];
    }

    const int e_own = col;
    const int exor  = (e_own & 15) << 4;

    int cur = 0;
    for (int t = tbeg; t < tend; ++t) {
        bar_vm();                                        // tile's DMA landed everywhere

        // issue next tile's gather (in flight across whole compute)
        #pragma unroll
        for (int j = 0; j < 4; ++j) nodeCur[j] = nodeNext[j];
        {
            char* nb = Alds + (cur ^ 1) * (TE * 512);
            #pragma unroll
            for (int j = 0; j < 4; ++j) {
                const _Float16* g = h16 + (size_t)nodeCur[j] * F + k16v[j] * 8;
                load_lds16(g, nb + (wave * 4 + j) * 1024);
            }
        }
        {
            int tn2 = t + 2; if (tn2 > NT - 1) tn2 = NT - 1;
            #pragma unroll
            for (int j = 0; j < 4; ++j) nodeNext[j] = idxp[tn2 * TE + eloc[j]];
        }

        const char* Ab = Alds + cur * (TE * 512);

        // ---- layer 1: X1^T = relu(W1 A^T + b1) ----
        f32x16 acc1 = {};
        #pragma unroll
        for (int kt = 0; kt < 16; ++kt) {
            const int c = (kt * 32 + 16 * h) ^ exor;
            f16x8 bf = *(const f16x8*)(Ab + e_own * 512 + c);
            acc1 = __builtin_amdgcn_mfma_f32_32x32x16_f16(w1a[kt], bf, acc1, 0, 0, 0);
        }
        #pragma unroll
        for (int g = 0; g < 4; ++g) {
            union { _Float16 q[4]; unsigned long long u; } pk;
            #pragma unroll
            for (int q = 0; q < 4; ++q) {
                float v = acc1[4 * g + q] + b1pl[4 * g + q];
                v = v > 0.f ? v : 0.f;
                pk.q[q] = (_Float16)v;
            }
            const int c = (mh * 64 + 16 * g + 8 * h) ^ exor;
            *(unsigned long long*)(Xlds + e_own * 256 + c) = pk.u;
        }
        bar_lgkm();                                      // X1 visible

        // ---- layer 2 (registers) ----
        f32x16 acc2 = {};
        #pragma unroll
        for (int kt = 0; kt < 8; ++kt) {
            const int c = (kt * 32 + 16 * h) ^ exor;
            f16x8 xf = *(const f16x8*)(Xlds + e_own * 256 + c);
            acc2 = __builtin_amdgcn_mfma_f32_32x32x16_f16(w2a[kt], xf, acc2, 0, 0, 0);
        }

        // ---- layer 3: lane-local dot ----
        float p = 0.f;
        #pragma unroll
        for (int r = 0; r < 16; ++r) {
            float v = acc2[r] + b2pl[r];
            v = v > 0.f ? v : 0.f;
            p = fmaf(w3pl[r], v, p);
        }
        p += __shfl_xor(p, 32);

        bar_lgkm();                                      // all X reads done (Spart alias)
        if (lane < 32) Spart[wave * 32 + lane] = p;
        bar_lgkm();                                      // Spart visible

        if (tid < TE) {
            float s = Spart[tid] + Spart[32 + tid] + Spart[64 + tid]
                    + Spart[96 + tid] + b3v;
            const int pe = perm[t * TE + tid];
            out[pe] = s;
        }
        cur ^= 1;
    }
    asm volatile("s_waitcnt vmcnt(0)" ::: "memory");     // drain trailing DMA before endpgm
}

// ---------------- fallback A: v4 (unsorted, HW-verified 99.9us) ----------------
__global__ __launch_bounds__(BLOCK) void edge_mlp_v4(
    const _Float16* __restrict__ h16,
    const int*   __restrict__ src,
    const int*   __restrict__ dst,
    const float* __restrict__ W1,
    const float* __restrict__ b1,
    const float* __restrict__ W2,
    const float* __restrict__ b2,
    const float* __restrict__ W3,
    const float* __restrict__ b3,
    float*       __restrict__ out)
{
    __shared__ __align__(128) char Alds[2 * TE * 512];
    __shared__ __align__(128) char Xlds[TE * 256];
    float* Spart = (float*)Xlds;

    const int tid  = threadIdx.x;
    const int wave = tid >> 6;
    const int lane = tid & 63;
    const int mh   = wave;
    const int col  = lane & 31;
    const int h    = lane >> 5;

    f16x8 w1a[16];
    #pragma unroll
    for (int kt = 0; kt < 16; ++kt) {
        const float* p = W1 + (mh * 32 + col) * 256 + kt * 16 + 8 * h;
        f16x8 v;
        #pragma unroll
        for (int j = 0; j < 8; ++j) v[j] = (_Float16)p[j];
        w1a[kt] = v;
    }
    f16x8 w2a[8];
    #pragma unroll
    for (int kt = 0; kt < 8; ++kt) {
        const float* p = W2 + (mh * 32 + col) * 128 + kt * 16 + 8 * h;
        f16x8 v;
        #pragma unroll
        for (int j = 0; j < 8; ++j) v[j] = (_Float16)p[j];
        w2a[kt] = v;
    }
    float b1pl[16], b2pl[16], w3pl[16];
    #pragma unroll
    for (int r = 0; r < 16; ++r) {
        const int row = mh * 32 + (r & 3) + 8 * (r >> 2) + 4 * h;
        b1pl[r] = b1[row];
        b2pl[r] = b2[row];
        w3pl[r] = W3[row];
    }
    const float b3v = b3[0];

    int eloc[4], k16v[4];
    #pragma unroll
    for (int j = 0; j < 4; ++j) {
        const int i = wave * 4 + j;
        eloc[j] = 2 * i + h;
        k16v[j] = (lane & 15) ^ (eloc[j] & 15);
    }
    const int whichv = (lane >> 4) & 1;
    const int* idxp  = whichv ? dst : src;

    const int t0 = blockIdx.x;
    int nodeCur[4], nodeNext[4];
    #pragma unroll
    for (int j = 0; j < 4; ++j) nodeCur[j] = idxp[t0 * TE + eloc[j]];
    #pragma unroll
    for (int j = 0; j < 4; ++j) {
        const _Float16* g = h16 + (size_t)nodeCur[j] * F + k16v[j] * 8;
        load_lds16(g, Alds + (wave * 4 + j) * 1024);
    }
    {
        int tn = t0 + GRID; if (tn > NT - 1) tn = NT - 1;
        #pragma unroll
        for (int j = 0; j < 4; ++j) nodeNext[j] = idxp[tn * TE + eloc[j]];
    }

    const int e_own = col;
    const int exor  = (e_own & 15) << 4;

    int cur = 0;
    for (int t = t0; t < NT; t += GRID) {
        bar_vm();
        #pragma unroll
        for (int j = 0; j < 4; ++j) nodeCur[j] = nodeNext[j];
        {
            char* nb = Alds + (cur ^ 1) * (TE * 512);
            #pragma unroll
            for (int j = 0; j < 4; ++j) {
                const _Float16* g = h16 + (size_t)nodeCur[j] * F + k16v[j] * 8;
                load_lds16(g, nb + (wave * 4 + j) * 1024);
            }
        }
        {
            int tn2 = t + 2 * GRID; if (tn2 > NT - 1) tn2 = NT - 1;
            #pragma unroll
            for (int j = 0; j < 4; ++j) nodeNext[j] = idxp[tn2 * TE + eloc[j]];
        }

        const char* Ab = Alds + cur * (TE * 512);

        f32x16 acc1 = {};
        #pragma unroll
        for (int kt = 0; kt < 16; ++kt) {
            const int c = (kt * 32 + 16 * h) ^ exor;
            f16x8 bf = *(const f16x8*)(Ab + e_own * 512 + c);
            acc1 = __builtin_amdgcn_mfma_f32_32x32x16_f16(w1a[kt], bf, acc1, 0, 0, 0);
        }
        #pragma unroll
        for (int g = 0; g < 4; ++g) {
            union { _Float16 q[4]; unsigned long long u; } pk;
            #pragma unroll
            for (int q = 0; q < 4; ++q) {
                float v = acc1[4 * g + q] + b1pl[4 * g + q];
                v = v > 0.f ? v : 0.f;
                pk.q[q] = (_Float16)v;
            }
            const int c = (mh * 64 + 16 * g + 8 * h) ^ exor;
            *(unsigned long long*)(Xlds + e_own * 256 + c) = pk.u;
        }
        bar_lgkm();

        f32x16 acc2 = {};
        #pragma unroll
        for (int kt = 0; kt < 8; ++kt) {
            const int c = (kt * 32 + 16 * h) ^ exor;
            f16x8 xf = *(const f16x8*)(Xlds + e_own * 256 + c);
            acc2 = __builtin_amdgcn_mfma_f32_32x32x16_f16(w2a[kt], xf, acc2, 0, 0, 0);
        }

        float p = 0.f;
        #pragma unroll
        for (int r = 0; r < 16; ++r) {
            float v = acc2[r] + b2pl[r];
            v = v > 0.f ? v : 0.f;
            p = fmaf(w3pl[r], v, p);
        }
        p += __shfl_xor(p, 32);

        bar_lgkm();
        if (lane < 32) Spart[wave * 32 + lane] = p;
        bar_lgkm();

        if (tid < TE) {
            float s = Spart[tid] + Spart[32 + tid] + Spart[64 + tid]
                    + Spart[96 + tid] + b3v;
            out[t * TE + tid] = s;
        }
        cur ^= 1;
    }
    asm volatile("s_waitcnt vmcnt(0)" ::: "memory");     // drain trailing DMA
}

// ---------------- fallback B: round-1 proven kernel ----------------
__global__ __launch_bounds__(512) void edge_mlp_v1(
    const float* __restrict__ h,
    const int*   __restrict__ src,
    const int*   __restrict__ dst,
    const float* __restrict__ W1,
    const float* __restrict__ b1,
    const float* __restrict__ W2,
    const float* __restrict__ b2,
    const float* __restrict__ W3,
    const float* __restrict__ b3,
    float*       __restrict__ out)
{
    __shared__ __align__(128) char Alds[64 * 512];
    __shared__ __align__(128) char Xlds[64 * 256];
    typedef float f32x4 __attribute__((ext_vector_type(4)));

    const int tid  = threadIdx.x;
    const int wave = tid >> 6;
    const int lane = tid & 63;
    const int l15  = lane & 15;
    const int lk   = lane >> 4;
    const int n1 = wave * 16 + l15;
    const int NT1 = (N_EDGES + 63) / 64;

    f16x8 w1f[8];
    #pragma unroll
    for (int kt = 0; kt < 8; ++kt) {
        const float* p = W1 + n1 * 256 + kt * 32 + lk * 8;
        f16x8 v;
        #pragma unroll
        for (int j = 0; j < 8; ++j) v[j] = (_Float16)p[j];
        w1f[kt] = v;
    }
    const float b1v = b1[n1];
    f16x8 w2f[4];
    #pragma unroll
    for (int kt = 0; kt < 4; ++kt) {
        const float* p = W2 + n1 * 128 + kt * 32 + lk * 8;
        f16x8 v;
        #pragma unroll
        for (int j = 0; j < 8; ++j) v[j] = (_Float16)p[j];
        w2f[kt] = v;
    }
    const float b2v = b2[n1];
    float w3r[16];
    {
        const float* p = W3 + (tid & 7) * 16;
        #pragma unroll
        for (int i = 0; i < 16; ++i) w3r[i] = p[i];
    }
    const float b3v = b3[0];

    const int slot = tid >> 2, part = tid & 3;
    const int g_e = slot >> 1, g_which = slot & 1;

    for (int t = blockIdx.x; t < NT1; t += gridDim.x) {
        {
            int eg = t * 64 + g_e;
            if (eg >= N_EDGES) eg = N_EDGES - 1;
            const int node = g_which ? dst[eg] : src[eg];
            const float* p = h + node * F + part * 32;
            const int kbase = g_which * 128 + part * 32;
            #pragma unroll
            for (int c = 0; c < 4; ++c) {
                float4 v0 = *(const float4*)(p + c * 8);
                float4 v1 = *(const float4*)(p + c * 8 + 4);
                f16x8 x;
                x[0] = (_Float16)v0.x; x[1] = (_Float16)v0.y;
                x[2] = (_Float16)v0.z; x[3] = (_Float16)v0.w;
                x[4] = (_Float16)v1.x; x[5] = (_Float16)v1.y;
                x[6] = (_Float16)v1.z; x[7] = (_Float16)v1.w;
                int byte = g_e * 512 + (kbase + c * 8) * 2;
                byte ^= (g_e & 7) << 4;
                *(f16x8*)(Alds + byte) = x;
            }
        }
        __syncthreads();
        #pragma unroll
        for (int m = 0; m < 4; ++m) {
            f32x4 acc = {0.f, 0.f, 0.f, 0.f};
            #pragma unroll
            for (int kt = 0; kt < 8; ++kt) {
                const int edge = m * 16 + l15;
                int byte = edge * 512 + (kt * 32 + lk * 8) * 2;
                byte ^= (edge & 7) << 4;
                f16x8 a = *(const f16x8*)(Alds + byte);
                acc = __builtin_amdgcn_mfma_f32_16x16x32_f16(a, w1f[kt], acc, 0, 0, 0);
            }
            #pragma unroll
            for (int r = 0; r < 4; ++r) {
                float v = acc[r] + b1v;
                v = v > 0.f ? v : 0.f;
                const int edge = m * 16 + lk * 4 + r;
                int byte = edge * 256 + n1 * 2;
                byte ^= (edge & 7) << 4;
                *(_Float16*)(Xlds + byte) = (_Float16)v;
            }
        }
        __syncthreads();
        f32x4 acc2[4];
        #pragma unroll
        for (int m = 0; m < 4; ++m) {
            f32x4 acc = {0.f, 0.f, 0.f, 0.f};
            #pragma unroll
            for (int kt = 0; kt < 4; ++kt) {
                const int edge = m * 16 + l15;
                int byte = edge * 256 + (kt * 32 + lk * 8) * 2;
                byte ^= (edge & 7) << 4;
                f16x8 a = *(const f16x8*)(Xlds + byte);
                acc = __builtin_amdgcn_mfma_f32_16x16x32_f16(a, w2f[kt], acc, 0, 0, 0);
            }
            acc2[m] = acc;
        }
        __syncthreads();
        #pragma unroll
        for (int m = 0; m < 4; ++m) {
            #pragma unroll
            for (int r = 0; r < 4; ++r) {
                float v = acc2[m][r] + b2v;
                v = v > 0.f ? v : 0.f;
                const int edge = m * 16 + lk * 4 + r;
                int byte = edge * 256 + n1 * 2;
                byte ^= (edge & 7) << 4;
                *(_Float16*)(Xlds + byte) = (_Float16)v;
            }
        }
        __syncthreads();
        {
            const int e_loc = tid >> 3;
            const int cgrp  = tid & 7;
            const int swz   = (e_loc & 7) << 4;
            const int base  = e_loc * 256 + cgrp * 32;
            f16x8 x0 = *(const f16x8*)(Xlds + (base ^ swz));
            f16x8 x1 = *(const f16x8*)(Xlds + ((base + 16) ^ swz));
            float p = 0.f;
            #pragma unroll
            for (int i = 0; i < 8; ++i) p += (float)x0[i] * w3r[i];
            #pragma unroll
            for (int i = 0; i < 8; ++i) p += (float)x1[i] * w3r[8 + i];
            p += __shfl_xor(p, 1);
            p += __shfl_xor(p, 2);
            p += __shfl_xor(p, 4);
            const int eg = t * 64 + e_loc;
            if (cgrp == 0 && eg < N_EDGES) out[eg] = p + b3v;
        }
    }
}

extern "C" void kernel_launch(void* const* d_in, const int* in_sizes, int n_in,
                              void* d_out, int out_size, void* d_ws, size_t ws_size,
                              hipStream_t stream) {
    const float* h   = (const float*)d_in[0];
    const int*   src = (const int*)  d_in[1];
    const int*   dst = (const int*)  d_in[2];
    const float* W1  = (const float*)d_in[3];
    const float* b1  = (const float*)d_in[4];
    const float* W2  = (const float*)d_in[5];
    const float* b2  = (const float*)d_in[6];
    const float* W3  = (const float*)d_in[7];
    const float* b3  = (const float*)d_in[8];
    float* out = (float*)d_out;

    const size_t H16B = (size_t)N_NODES * F * sizeof(_Float16);   // 25,600,000
    const size_t SOFF = H16B;
    const size_t DOFF = SOFF + (size_t)N_EDGES * 4;               // +2,000,000
    const size_t POFF = DOFF + (size_t)N_EDGES * 4;
    const size_t BOFF = POFF + (size_t)N_EDGES * 4;
    const size_t NEED_SORT = BOFF + (size_t)HB * NB * 4;          // ~31.8 MB

    char* ws = (char*)d_ws;
    if (ws_size >= NEED_SORT) {
        _Float16* h16  = (_Float16*)ws;
        int*      s_srt = (int*)(ws + SOFF);
        int*      d_srt = (int*)(ws + DOFF);
        int*      perm  = (int*)(ws + POFF);
        unsigned* bh    = (unsigned*)(ws + BOFF);
        h_to_f16<<<6250, 256, 0, stream>>>(h, h16);
        hist_kernel<<<HB, 256, 0, stream>>>(src, bh);
        scan_kernel<<<1, 256, 0, stream>>>(bh);
        scatter_kernel<<<HB, 256, 0, stream>>>(src, dst, bh, s_srt, d_srt, perm);
        edge_mlp_v6<<<GRID, BLOCK, 0, stream>>>(h16, s_srt, d_srt, perm,
                                                W1, b1, W2, b2, W3, b3, out);
    } else if (ws_size >= H16B) {
        _Float16* h16 = (_Float16*)ws;
        h_to_f16<<<6250, 256, 0, stream>>>(h, h16);
        edge_mlp_v4<<<GRID, BLOCK, 0, stream>>>(h16, src, dst, W1, b1, W2, b2, W3, b3, out);
    } else {
        edge_mlp_v1<<<512, 512, 0, stream>>>(h, src, dst, W1, b1, W2, b2, W3, b3, out);
    }
}